// Round 1
// baseline (793.850 us; speedup 1.0000x reference)
//
#include <hip/hip_runtime.h>

// -------- dtype detection: edge_index may be int32 or int64 --------
// int64 node indices are < 2^17, so every odd 32-bit word is 0.
// 256 consecutive zeros at odd positions from random int32 indices ~never happens.
__global__ void detect_i64(const int* __restrict__ e, int* __restrict__ flag) {
    if (threadIdx.x == 0 && blockIdx.x == 0) {
        int all0 = 1;
        for (int i = 0; i < 256; ++i) {
            if (e[2 * i + 1] != 0) { all0 = 0; break; }
        }
        *flag = all0;
    }
}

// -------- fused dual-GEMM: outRel = act(in)@Wrel.T ; outRoot = act(in)@Wroot.T + b --------
// act = relu if relu_in. Safe for in == outRoot (rows staged to LDS before write).
__global__ __launch_bounds__(256) void transform_k(
    const float* __restrict__ in, const float* __restrict__ Wrel,
    const float* __restrict__ Wroot, const float* __restrict__ bias,
    float* __restrict__ outRel, float* __restrict__ outRoot,
    int nrows, int relu_in)
{
    __shared__ float Wr[64][65];   // Wr[k][j] = Wrel[j][k]  (transposed, conflict-free reads)
    __shared__ float Wo[64][65];
    __shared__ float Xs[32][64];   // 32-row input tile
    __shared__ float Bs[64];

    const int tid = threadIdx.x;
    for (int idx = tid; idx < 4096; idx += 256) {
        int j = idx >> 6, k = idx & 63;
        Wr[k][j] = Wrel[idx];
        Wo[k][j] = Wroot[idx];
    }
    if (tid < 64) Bs[tid] = bias[tid];

    const int lane = tid & 63;
    const int wid  = tid >> 6;
    const float4* in4 = (const float4*)in;

    for (int tile = blockIdx.x * 32; tile < nrows; tile += gridDim.x * 32) {
        __syncthreads();   // covers W/B load on first iter + Xs reuse on later iters
        int nrem = min(32, nrows - tile);
        for (int idx = tid; idx < nrem * 16; idx += 256) {
            int r = idx >> 4, q = idx & 15;
            float4 v = in4[(size_t)(tile + r) * 16 + q];
            if (relu_in) {
                v.x = fmaxf(v.x, 0.f); v.y = fmaxf(v.y, 0.f);
                v.z = fmaxf(v.z, 0.f); v.w = fmaxf(v.w, 0.f);
            }
            *((float4*)&Xs[r][0] + q) = v;
        }
        __syncthreads();

        float b = Bs[lane];
        float accR[8], accO[8];
#pragma unroll
        for (int r = 0; r < 8; ++r) { accR[r] = 0.f; accO[r] = b; }

        for (int k = 0; k < 64; ++k) {
            float wr = Wr[k][lane];
            float wo = Wo[k][lane];
#pragma unroll
            for (int r = 0; r < 8; ++r) {
                float xv = Xs[wid * 8 + r][k];   // wave-uniform -> LDS broadcast
                accR[r] = fmaf(xv, wr, accR[r]);
                accO[r] = fmaf(xv, wo, accO[r]);
            }
        }
#pragma unroll
        for (int r = 0; r < 8; ++r) {
            int row = tile + wid * 8 + r;
            if (row < nrows) {
                outRel[(size_t)row * 64 + lane]  = accR[r];
                outRoot[(size_t)row * 64 + lane] = accO[r];
            }
        }
    }
}

// -------- edge scatter-add: dstf[dst] += srcf[src], one wave per edge --------
__global__ __launch_bounds__(256) void scatter_add_k(
    const int* __restrict__ e32, const long long* __restrict__ e64,
    const int* __restrict__ flag, const float* __restrict__ srcf,
    float* dstf, int E)
{
    int edge = blockIdx.x * 4 + (threadIdx.x >> 6);
    if (edge >= E) return;
    int lane = threadIdx.x & 63;
    int s, d;
    if (*flag) {
        s = (int)e64[edge];
        d = (int)e64[(size_t)E + edge];
    } else {
        s = e32[edge];
        d = e32[(size_t)E + edge];
    }
    float v = srcf[(size_t)s * 64 + lane];
    unsafeAtomicAdd(&dstf[(size_t)d * 64 + lane], v);   // global_atomic_add_f32
}

// -------- FC head: out[n] = relu(h[n]) . Wfc + bfc --------
__global__ __launch_bounds__(256) void final_fc_k(
    const float* __restrict__ h, const float* __restrict__ Wfc,
    const float* __restrict__ bfc, float* __restrict__ out, int nrows)
{
    int n = blockIdx.x * 256 + threadIdx.x;
    if (n >= nrows) return;
    float acc = bfc[0];
    const float4* hp = (const float4*)(h + (size_t)n * 64);
    const float4* wp = (const float4*)Wfc;
#pragma unroll
    for (int q = 0; q < 16; ++q) {
        float4 v = hp[q];
        float4 w = wp[q];
        acc += fmaxf(v.x, 0.f) * w.x + fmaxf(v.y, 0.f) * w.y
             + fmaxf(v.z, 0.f) * w.z + fmaxf(v.w, 0.f) * w.w;
    }
    out[n] = acc;
}

extern "C" void kernel_launch(void* const* d_in, const int* in_sizes, int n_in,
                              void* d_out, int out_size, void* d_ws, size_t ws_size,
                              hipStream_t stream) {
    const float* x       = (const float*)d_in[0];
    const int* e32       = (const int*)d_in[1];
    const long long* e64 = (const long long*)d_in[1];
    const float* W1_rel  = (const float*)d_in[2];
    const float* W1_root = (const float*)d_in[3];
    const float* b1      = (const float*)d_in[4];
    const float* W2_rel  = (const float*)d_in[5];
    const float* W2_root = (const float*)d_in[6];
    const float* b2      = (const float*)d_in[7];
    const float* W_fc    = (const float*)d_in[8];
    const float* b_fc    = (const float*)d_in[9];
    float* out           = (float*)d_out;

    const int N = in_sizes[0] / 64;    // 100000
    const int E = in_sizes[1] / 2;     // 1600000

    float* bufA = (float*)d_ws;                       // N*64 f32: transformed-rel features
    float* bufB = bufA + (size_t)N * 64;              // N*64 f32: layer accumulator / h
    int*   flag = (int*)(bufB + (size_t)N * 64);      // dtype flag

    detect_i64<<<1, 64, 0, stream>>>(e32, flag);

    // layer 1: bufA = x@W1_rel.T ; bufB = x@W1_root.T + b1
    transform_k<<<1024, 256, 0, stream>>>(x, W1_rel, W1_root, b1, bufA, bufB, N, 0);
    // bufB[dst] += bufA[src]
    scatter_add_k<<<(E + 3) / 4, 256, 0, stream>>>(e32, e64, flag, bufA, bufB, E);

    // layer 2 (relu folded on read; in-place on bufB)
    transform_k<<<1024, 256, 0, stream>>>(bufB, W2_rel, W2_root, b2, bufA, bufB, N, 1);
    scatter_add_k<<<(E + 3) / 4, 256, 0, stream>>>(e32, e64, flag, bufA, bufB, E);

    // head (relu folded)
    final_fc_k<<<(N + 255) / 256, 256, 0, stream>>>(bufB, W_fc, b_fc, out, N);
}

// Round 2
// 418.860 us; speedup vs baseline: 1.8953x; 1.8953x over previous
//
#include <hip/hip_runtime.h>
#include <hip/hip_bf16.h>

// ============ dtype detection: edge_index may be int32 or int64 ============
__global__ void detect_i64(const int* __restrict__ e, int* __restrict__ flag) {
    if (threadIdx.x == 0 && blockIdx.x == 0) {
        int all0 = 1;
        for (int i = 0; i < 256; ++i) {
            if (e[2 * i + 1] != 0) { all0 = 0; break; }
        }
        *flag = all0;
    }
}

// ============ CSR build ============
__global__ __launch_bounds__(256) void zero_k(int* __restrict__ cnt, int n) {
    int i = blockIdx.x * 256 + threadIdx.x;
    if (i < n) cnt[i] = 0;
}

__global__ __launch_bounds__(256) void hist_k(
    const int* __restrict__ e32, const long long* __restrict__ e64,
    const int* __restrict__ flag, int* __restrict__ cnt, int E)
{
    int i = blockIdx.x * 256 + threadIdx.x;
    if (i >= E) return;
    int d = (*flag) ? (int)e64[(size_t)E + i] : e32[(size_t)E + i];
    atomicAdd(&cnt[d], 1);
}

// chunk = 1024 counters per block
__global__ __launch_bounds__(256) void scan1_k(const int* __restrict__ cnt,
                                               int* __restrict__ part, int N) {
    __shared__ int ts[256];
    int t = threadIdx.x, c0 = blockIdx.x * 1024;
    int s = 0;
#pragma unroll
    for (int j = 0; j < 4; ++j) { int i = c0 + t * 4 + j; if (i < N) s += cnt[i]; }
    ts[t] = s; __syncthreads();
    for (int off = 128; off > 0; off >>= 1) {
        if (t < off) ts[t] += ts[t + off];
        __syncthreads();
    }
    if (t == 0) part[blockIdx.x] = ts[0];
}

__global__ __launch_bounds__(128) void scan2_k(const int* __restrict__ part,
                                               int* __restrict__ part_ex,
                                               int* __restrict__ row_ptr, int B, int N) {
    __shared__ int ls[129];
    int t = threadIdx.x;
    if (t < B) ls[t] = part[t];
    __syncthreads();
    if (t == 0) {
        int run = 0;
        for (int i = 0; i < B; ++i) { int v = ls[i]; ls[i] = run; run += v; }
        ls[B] = run;
        row_ptr[N] = run;
    }
    __syncthreads();
    if (t <= B) part_ex[t] = ls[t];
}

__global__ __launch_bounds__(256) void scan3_k(const int* __restrict__ cnt,
                                               const int* __restrict__ part_ex,
                                               int* __restrict__ row_ptr,
                                               int* __restrict__ cursor, int N) {
    __shared__ int ts[256];
    int t = threadIdx.x, c0 = blockIdx.x * 1024;
    int v[4], s = 0;
#pragma unroll
    for (int j = 0; j < 4; ++j) { int i = c0 + t * 4 + j; v[j] = (i < N) ? cnt[i] : 0; s += v[j]; }
    ts[t] = s; __syncthreads();
    for (int off = 1; off < 256; off <<= 1) {
        int x = (t >= off) ? ts[t - off] : 0;
        __syncthreads();
        ts[t] += x;
        __syncthreads();
    }
    int base = part_ex[blockIdx.x] + ts[t] - s;
#pragma unroll
    for (int j = 0; j < 4; ++j) {
        int i = c0 + t * 4 + j;
        if (i < N) { row_ptr[i] = base; cursor[i] = base; base += v[j]; }
    }
}

__global__ __launch_bounds__(256) void fill_k(
    const int* __restrict__ e32, const long long* __restrict__ e64,
    const int* __restrict__ flag, int* __restrict__ cursor,
    int* __restrict__ csr, int E)
{
    int i = blockIdx.x * 256 + threadIdx.x;
    if (i >= E) return;
    int s, d;
    if (*flag) { s = (int)e64[i]; d = (int)e64[(size_t)E + i]; }
    else       { s = e32[i];      d = e32[(size_t)E + i]; }
    int pos = atomicAdd(&cursor[d], 1);
    csr[pos] = s;
}

// ============ fused dual-GEMM: rel(bf16) = act(in)@Wrel.T ; root(f32) = act(in)@Wroot.T + b ============
__global__ __launch_bounds__(256) void transform_k(
    const float* __restrict__ in, const float* __restrict__ Wrel,
    const float* __restrict__ Wroot, const float* __restrict__ bias,
    __hip_bfloat16* __restrict__ outRel, float* __restrict__ outRoot,
    int nrows, int relu_in)
{
    __shared__ float Wr[64][65];
    __shared__ float Wo[64][65];
    __shared__ float Xs[32][64];
    __shared__ float Bs[64];

    const int tid = threadIdx.x;
    for (int idx = tid; idx < 4096; idx += 256) {
        int j = idx >> 6, k = idx & 63;
        Wr[k][j] = Wrel[idx];
        Wo[k][j] = Wroot[idx];
    }
    if (tid < 64) Bs[tid] = bias[tid];

    const int lane = tid & 63;
    const int wid  = tid >> 6;
    const float4* in4 = (const float4*)in;

    for (int tile = blockIdx.x * 32; tile < nrows; tile += gridDim.x * 32) {
        __syncthreads();
        int nrem = min(32, nrows - tile);
        for (int idx = tid; idx < nrem * 16; idx += 256) {
            int r = idx >> 4, q = idx & 15;
            float4 v = in4[(size_t)(tile + r) * 16 + q];
            if (relu_in) {
                v.x = fmaxf(v.x, 0.f); v.y = fmaxf(v.y, 0.f);
                v.z = fmaxf(v.z, 0.f); v.w = fmaxf(v.w, 0.f);
            }
            *((float4*)&Xs[r][0] + q) = v;
        }
        __syncthreads();

        float b = Bs[lane];
        float accR[8], accO[8];
#pragma unroll
        for (int r = 0; r < 8; ++r) { accR[r] = 0.f; accO[r] = b; }

        for (int k = 0; k < 64; ++k) {
            float wr = Wr[k][lane];
            float wo = Wo[k][lane];
#pragma unroll
            for (int r = 0; r < 8; ++r) {
                float xv = Xs[wid * 8 + r][k];
                accR[r] = fmaf(xv, wr, accR[r]);
                accO[r] = fmaf(xv, wo, accO[r]);
            }
        }
#pragma unroll
        for (int r = 0; r < 8; ++r) {
            int row = tile + wid * 8 + r;
            if (row < nrows) {
                outRel[(size_t)row * 64 + lane]  = __float2bfloat16(accR[r]);
                outRoot[(size_t)row * 64 + lane] = accO[r];
            }
        }
    }
}

// ============ CSR gather-aggregate: acc[n] += sum_{e in CSR[n]} rel[csr[e]] ============
__global__ __launch_bounds__(256) void agg_k(
    const int* __restrict__ row_ptr, const int* __restrict__ csr,
    const unsigned short* __restrict__ rel, float* __restrict__ accb, int N)
{
    int node = blockIdx.x * 4 + (threadIdx.x >> 6);
    if (node >= N) return;
    int lane = threadIdx.x & 63;
    int start = row_ptr[node], end = row_ptr[node + 1];
    float acc = accb[(size_t)node * 64 + lane];
    int e = start;
    for (; e + 4 <= end; e += 4) {
        int s0 = csr[e], s1 = csr[e + 1], s2 = csr[e + 2], s3 = csr[e + 3];
        unsigned short a0 = rel[(size_t)s0 * 64 + lane];
        unsigned short a1 = rel[(size_t)s1 * 64 + lane];
        unsigned short a2 = rel[(size_t)s2 * 64 + lane];
        unsigned short a3 = rel[(size_t)s3 * 64 + lane];
        acc += __uint_as_float((unsigned)a0 << 16) + __uint_as_float((unsigned)a1 << 16)
             + __uint_as_float((unsigned)a2 << 16) + __uint_as_float((unsigned)a3 << 16);
    }
    for (; e < end; ++e)
        acc += __uint_as_float((unsigned)rel[(size_t)csr[e] * 64 + lane] << 16);
    accb[(size_t)node * 64 + lane] = acc;
}

// ============ FC head ============
__global__ __launch_bounds__(256) void final_fc_k(
    const float* __restrict__ h, const float* __restrict__ Wfc,
    const float* __restrict__ bfc, float* __restrict__ out, int nrows)
{
    int n = blockIdx.x * 256 + threadIdx.x;
    if (n >= nrows) return;
    float acc = bfc[0];
    const float4* hp = (const float4*)(h + (size_t)n * 64);
    const float4* wp = (const float4*)Wfc;
#pragma unroll
    for (int q = 0; q < 16; ++q) {
        float4 v = hp[q];
        float4 w = wp[q];
        acc += fmaxf(v.x, 0.f) * w.x + fmaxf(v.y, 0.f) * w.y
             + fmaxf(v.z, 0.f) * w.z + fmaxf(v.w, 0.f) * w.w;
    }
    out[n] = acc;
}

extern "C" void kernel_launch(void* const* d_in, const int* in_sizes, int n_in,
                              void* d_out, int out_size, void* d_ws, size_t ws_size,
                              hipStream_t stream) {
    const float* x       = (const float*)d_in[0];
    const int* e32       = (const int*)d_in[1];
    const long long* e64 = (const long long*)d_in[1];
    const float* W1_rel  = (const float*)d_in[2];
    const float* W1_root = (const float*)d_in[3];
    const float* b1      = (const float*)d_in[4];
    const float* W2_rel  = (const float*)d_in[5];
    const float* W2_root = (const float*)d_in[6];
    const float* b2      = (const float*)d_in[7];
    const float* W_fc    = (const float*)d_in[8];
    const float* b_fc    = (const float*)d_in[9];
    float* out           = (float*)d_out;

    const int N = in_sizes[0] / 64;    // 100000
    const int E = in_sizes[1] / 2;     // 1600000

    // workspace layout (~46 MB)
    char* p = (char*)d_ws;
    float* bufB = (float*)p;                 p += (size_t)N * 64 * 4;   // root/accum f32
    __hip_bfloat16* bufA = (__hip_bfloat16*)p; p += (size_t)N * 64 * 2; // rel bf16
    int* csr     = (int*)p;  p += (size_t)E * 4;
    int* row_ptr = (int*)p;  p += (size_t)(N + 1) * 4;
    int* cursor  = (int*)p;  p += (size_t)N * 4;
    int* cnt     = (int*)p;  p += (size_t)N * 4;
    int* part    = (int*)p;  p += 256 * 4;
    int* part_ex = (int*)p;  p += 257 * 4;
    int* flag    = (int*)p;

    const int B = (N + 1023) / 1024;   // scan chunks

    detect_i64<<<1, 64, 0, stream>>>(e32, flag);

    // ---- CSR build (dst-sorted) ----
    zero_k<<<(N + 255) / 256, 256, 0, stream>>>(cnt, N);
    hist_k<<<(E + 255) / 256, 256, 0, stream>>>(e32, e64, flag, cnt, E);
    scan1_k<<<B, 256, 0, stream>>>(cnt, part, N);
    scan2_k<<<1, 128, 0, stream>>>(part, part_ex, row_ptr, B, N);
    scan3_k<<<B, 256, 0, stream>>>(cnt, part_ex, row_ptr, cursor, N);
    fill_k<<<(E + 255) / 256, 256, 0, stream>>>(e32, e64, flag, cursor, csr, E);

    // ---- layer 1 ----
    transform_k<<<1024, 256, 0, stream>>>(x, W1_rel, W1_root, b1, bufA, bufB, N, 0);
    agg_k<<<(N + 3) / 4, 256, 0, stream>>>(row_ptr, csr, (const unsigned short*)bufA, bufB, N);

    // ---- layer 2 (relu folded on read; in-place on bufB) ----
    transform_k<<<1024, 256, 0, stream>>>(bufB, W2_rel, W2_root, b2, bufA, bufB, N, 1);
    agg_k<<<(N + 3) / 4, 256, 0, stream>>>(row_ptr, csr, (const unsigned short*)bufA, bufB, N);

    // ---- head ----
    final_fc_k<<<(N + 255) / 256, 256, 0, stream>>>(bufB, W_fc, b_fc, out, N);
}

// Round 3
// 267.317 us; speedup vs baseline: 2.9697x; 1.5669x over previous
//
#include <hip/hip_runtime.h>
#include <hip/hip_bf16.h>

// ============ dtype detection: edge_index may be int32 or int64 ============
__global__ void detect_i64(const int* __restrict__ e, int* __restrict__ flag) {
    if (threadIdx.x == 0 && blockIdx.x == 0) {
        int all0 = 1;
        for (int i = 0; i < 256; ++i) {
            if (e[2 * i + 1] != 0) { all0 = 0; break; }
        }
        *flag = all0;
    }
}

// ============ deterministic two-level binning CSR build ============
// bucket = dst >> BSHIFT (128 nodes/bucket). NB <= 1024, B1 <= 256 required.

// Pass A1: per-block bucket histogram (LDS atomics only), coalesced global write.
__global__ __launch_bounds__(256) void bin_hist_k(
    const int* __restrict__ e32, const long long* __restrict__ e64,
    const int* __restrict__ flag, int* __restrict__ blockhist /*[B1][NB]*/,
    int E, int NB, int bshift, int chunk)
{
    __shared__ int hist[1024];
    const int tid = threadIdx.x;
    for (int i = tid; i < NB; i += 256) hist[i] = 0;
    __syncthreads();
    const int base = blockIdx.x * chunk;
    const int end  = min(base + chunk, E);
    const bool i64 = (*flag != 0);
    for (int i = base + tid; i < end; i += 256) {
        int d = i64 ? (int)e64[(size_t)E + i] : e32[(size_t)E + i];
        atomicAdd(&hist[d >> bshift], 1);
    }
    __syncthreads();
    int* row = blockhist + (size_t)blockIdx.x * NB;
    for (int b = tid; b < NB; b += 256) row[b] = hist[b];
}

// scanA: one block per bucket; exclusive scan over its B1 block-counts.
__global__ __launch_bounds__(256) void scanA_k(
    const int* __restrict__ blockhist /*[B1][NB]*/, int* __restrict__ bh_ex /*[NB][B1]*/,
    int* __restrict__ btot, int NB, int B1)
{
    __shared__ int v[256];
    const int t = threadIdx.x, b = blockIdx.x;
    int x = (t < B1) ? blockhist[(size_t)t * NB + b] : 0;
    v[t] = x; __syncthreads();
    for (int off = 1; off < 256; off <<= 1) {
        int y = (t >= off) ? v[t - off] : 0;
        __syncthreads();
        v[t] += y;
        __syncthreads();
    }
    if (t < B1) bh_ex[(size_t)b * B1 + t] = v[t] - x;   // exclusive
    if (t == 255) btot[b] = v[255];
}

// scanB: exclusive scan over NB bucket totals -> bucket_base; also row_ptr[N]=E.
__global__ __launch_bounds__(256) void scanB_k(
    const int* __restrict__ btot, int* __restrict__ bucket_base,
    int* __restrict__ row_ptr, int NB, int N)
{
    __shared__ int ts[256];
    const int t = threadIdx.x;
    int v[4], s = 0;
#pragma unroll
    for (int j = 0; j < 4; ++j) { int i = t * 4 + j; v[j] = (i < NB) ? btot[i] : 0; s += v[j]; }
    ts[t] = s; __syncthreads();
    for (int off = 1; off < 256; off <<= 1) {
        int x = (t >= off) ? ts[t - off] : 0;
        __syncthreads();
        ts[t] += x;
        __syncthreads();
    }
    int base = ts[t] - s;
#pragma unroll
    for (int j = 0; j < 4; ++j) {
        int i = t * 4 + j;
        if (i < NB) { bucket_base[i] = base; base += v[j]; }
    }
    if (t == 255) { bucket_base[NB] = ts[255]; row_ptr[N] = ts[255]; }
}

// Pass A2: scatter packed (src<<bshift | dstloc) into bucket regions, LDS cursors.
__global__ __launch_bounds__(256) void bin_scatter_k(
    const int* __restrict__ e32, const long long* __restrict__ e64,
    const int* __restrict__ flag, const int* __restrict__ bh_ex /*[NB][B1]*/,
    const int* __restrict__ bucket_base, int* __restrict__ pairs,
    int E, int NB, int B1, int bshift, int chunk)
{
    __shared__ int ofs[1024];
    __shared__ int cnt[1024];
    const int tid = threadIdx.x;
    for (int b = tid; b < NB; b += 256) {
        ofs[b] = bucket_base[b] + bh_ex[(size_t)b * B1 + blockIdx.x];
        cnt[b] = 0;
    }
    __syncthreads();
    const int base = blockIdx.x * chunk;
    const int end  = min(base + chunk, E);
    const bool i64 = (*flag != 0);
    const int mask = (1 << bshift) - 1;
    for (int i = base + tid; i < end; i += 256) {
        int s, d;
        if (i64) { s = (int)e64[i]; d = (int)e64[(size_t)E + i]; }
        else     { s = e32[i];      d = e32[(size_t)E + i]; }
        int b = d >> bshift;
        int r = atomicAdd(&cnt[b], 1);
        pairs[ofs[b] + r] = (s << bshift) | (d & mask);
    }
}

// Pass B: per bucket, node-level histogram+scan in LDS -> row_ptr + csr.
__global__ __launch_bounds__(256) void buildcsr_k(
    const int* __restrict__ pairs, const int* __restrict__ bucket_base,
    int* __restrict__ row_ptr, int* __restrict__ csr, int N, int bshift)
{
    __shared__ int nh[128];
    __shared__ int sc[128];
    __shared__ int cur[128];
    const int t = threadIdx.x, b = blockIdx.x;
    const int n0 = b << bshift;
    const int nn = min(1 << bshift, N - n0);
    const int start = bucket_base[b], end = bucket_base[b + 1];
    const int mask = (1 << bshift) - 1;

    if (t < 128) nh[t] = 0;
    __syncthreads();
    for (int i = start + t; i < end; i += 256)
        atomicAdd(&nh[pairs[i] & mask], 1);
    __syncthreads();
    if (t < 128) sc[t] = nh[t];
    __syncthreads();
    for (int off = 1; off < 128; off <<= 1) {
        int y = (t < 128 && t >= off) ? sc[t - off] : 0;
        __syncthreads();
        if (t < 128) sc[t] += y;
        __syncthreads();
    }
    if (t < nn) {
        int rp = start + sc[t] - nh[t];
        row_ptr[n0 + t] = rp;
        cur[t] = rp;
    }
    __syncthreads();
    for (int i = start + t; i < end; i += 256) {
        int p = pairs[i];
        int dloc = p & mask;
        int pos = atomicAdd(&cur[dloc], 1);
        csr[pos] = p >> bshift;
    }
}

// ============ fused dual-GEMM: rel(bf16) = act(in)@Wrel.T ; root(f32) = act(in)@Wroot.T + b ============
__global__ __launch_bounds__(256) void transform_k(
    const float* __restrict__ in, const float* __restrict__ Wrel,
    const float* __restrict__ Wroot, const float* __restrict__ bias,
    __hip_bfloat16* __restrict__ outRel, float* __restrict__ outRoot,
    int nrows, int relu_in)
{
    __shared__ float Wr[64][65];
    __shared__ float Wo[64][65];
    __shared__ float Xs[32][64];
    __shared__ float Bs[64];

    const int tid = threadIdx.x;
    for (int idx = tid; idx < 4096; idx += 256) {
        int j = idx >> 6, k = idx & 63;
        Wr[k][j] = Wrel[idx];
        Wo[k][j] = Wroot[idx];
    }
    if (tid < 64) Bs[tid] = bias[tid];

    const int lane = tid & 63;
    const int wid  = tid >> 6;
    const float4* in4 = (const float4*)in;

    for (int tile = blockIdx.x * 32; tile < nrows; tile += gridDim.x * 32) {
        __syncthreads();
        int nrem = min(32, nrows - tile);
        for (int idx = tid; idx < nrem * 16; idx += 256) {
            int r = idx >> 4, q = idx & 15;
            float4 v = in4[(size_t)(tile + r) * 16 + q];
            if (relu_in) {
                v.x = fmaxf(v.x, 0.f); v.y = fmaxf(v.y, 0.f);
                v.z = fmaxf(v.z, 0.f); v.w = fmaxf(v.w, 0.f);
            }
            *((float4*)&Xs[r][0] + q) = v;
        }
        __syncthreads();

        float b = Bs[lane];
        float accR[8], accO[8];
#pragma unroll
        for (int r = 0; r < 8; ++r) { accR[r] = 0.f; accO[r] = b; }

        for (int k = 0; k < 64; ++k) {
            float wr = Wr[k][lane];
            float wo = Wo[k][lane];
#pragma unroll
            for (int r = 0; r < 8; ++r) {
                float xv = Xs[wid * 8 + r][k];
                accR[r] = fmaf(xv, wr, accR[r]);
                accO[r] = fmaf(xv, wo, accO[r]);
            }
        }
#pragma unroll
        for (int r = 0; r < 8; ++r) {
            int row = tile + wid * 8 + r;
            if (row < nrows) {
                outRel[(size_t)row * 64 + lane]  = __float2bfloat16(accR[r]);
                outRoot[(size_t)row * 64 + lane] = accO[r];
            }
        }
    }
}

// ============ CSR gather-aggregate: acc[n] += sum_{e in CSR[n]} rel[csr[e]] ============
__global__ __launch_bounds__(256) void agg_k(
    const int* __restrict__ row_ptr, const int* __restrict__ csr,
    const unsigned short* __restrict__ rel, float* __restrict__ accb, int N)
{
    int node = blockIdx.x * 4 + (threadIdx.x >> 6);
    if (node >= N) return;
    int lane = threadIdx.x & 63;
    int start = row_ptr[node], end = row_ptr[node + 1];
    float acc = accb[(size_t)node * 64 + lane];
    int e = start;
    for (; e + 4 <= end; e += 4) {
        int s0 = csr[e], s1 = csr[e + 1], s2 = csr[e + 2], s3 = csr[e + 3];
        unsigned short a0 = rel[(size_t)s0 * 64 + lane];
        unsigned short a1 = rel[(size_t)s1 * 64 + lane];
        unsigned short a2 = rel[(size_t)s2 * 64 + lane];
        unsigned short a3 = rel[(size_t)s3 * 64 + lane];
        acc += __uint_as_float((unsigned)a0 << 16) + __uint_as_float((unsigned)a1 << 16)
             + __uint_as_float((unsigned)a2 << 16) + __uint_as_float((unsigned)a3 << 16);
    }
    for (; e < end; ++e)
        acc += __uint_as_float((unsigned)rel[(size_t)csr[e] * 64 + lane] << 16);
    accb[(size_t)node * 64 + lane] = acc;
}

// ============ FC head ============
__global__ __launch_bounds__(256) void final_fc_k(
    const float* __restrict__ h, const float* __restrict__ Wfc,
    const float* __restrict__ bfc, float* __restrict__ out, int nrows)
{
    int n = blockIdx.x * 256 + threadIdx.x;
    if (n >= nrows) return;
    float acc = bfc[0];
    const float4* hp = (const float4*)(h + (size_t)n * 64);
    const float4* wp = (const float4*)Wfc;
#pragma unroll
    for (int q = 0; q < 16; ++q) {
        float4 v = hp[q];
        float4 w = wp[q];
        acc += fmaxf(v.x, 0.f) * w.x + fmaxf(v.y, 0.f) * w.y
             + fmaxf(v.z, 0.f) * w.z + fmaxf(v.w, 0.f) * w.w;
    }
    out[n] = acc;
}

extern "C" void kernel_launch(void* const* d_in, const int* in_sizes, int n_in,
                              void* d_out, int out_size, void* d_ws, size_t ws_size,
                              hipStream_t stream) {
    const float* x       = (const float*)d_in[0];
    const int* e32       = (const int*)d_in[1];
    const long long* e64 = (const long long*)d_in[1];
    const float* W1_rel  = (const float*)d_in[2];
    const float* W1_root = (const float*)d_in[3];
    const float* b1      = (const float*)d_in[4];
    const float* W2_rel  = (const float*)d_in[5];
    const float* W2_root = (const float*)d_in[6];
    const float* b2      = (const float*)d_in[7];
    const float* W_fc    = (const float*)d_in[8];
    const float* b_fc    = (const float*)d_in[9];
    float* out           = (float*)d_out;

    const int N = in_sizes[0] / 64;    // 100000
    const int E = in_sizes[1] / 2;     // 1600000

    // binning parameters: NB <= 1024, B1 <= 256 (true for N=100K, E=1.6M)
    int bshift = 7;
    while ((((size_t)N + (1u << bshift) - 1) >> bshift) > 1024) bshift++;
    const int NB = (N + (1 << bshift) - 1) >> bshift;      // 782
    int chunk = 8192;
    while ((E + chunk - 1) / chunk > 256) chunk <<= 1;
    const int B1 = (E + chunk - 1) / chunk;                // 196

    // workspace layout (~52.5 MB)
    char* p = (char*)d_ws;
    float* bufB = (float*)p;                   p += (size_t)N * 64 * 4;   // root/accum f32
    __hip_bfloat16* bufA = (__hip_bfloat16*)p; p += (size_t)N * 64 * 2;   // rel bf16
    int* csr         = (int*)p;  p += (size_t)E * 4;
    int* pairs       = (int*)p;  p += (size_t)E * 4;
    int* row_ptr     = (int*)p;  p += (size_t)(N + 1) * 4;
    int* blockhist   = (int*)p;  p += (size_t)B1 * NB * 4;
    int* bh_ex       = (int*)p;  p += (size_t)NB * B1 * 4;
    int* btot        = (int*)p;  p += (size_t)NB * 4;
    int* bucket_base = (int*)p;  p += (size_t)(NB + 1) * 4;
    int* flag        = (int*)p;

    detect_i64<<<1, 64, 0, stream>>>(e32, flag);

    // ---- CSR build (deterministic binning; LDS atomics only) ----
    bin_hist_k<<<B1, 256, 0, stream>>>(e32, e64, flag, blockhist, E, NB, bshift, chunk);
    scanA_k<<<NB, 256, 0, stream>>>(blockhist, bh_ex, btot, NB, B1);
    scanB_k<<<1, 256, 0, stream>>>(btot, bucket_base, row_ptr, NB, N);
    bin_scatter_k<<<B1, 256, 0, stream>>>(e32, e64, flag, bh_ex, bucket_base, pairs,
                                          E, NB, B1, bshift, chunk);
    buildcsr_k<<<NB, 256, 0, stream>>>(pairs, bucket_base, row_ptr, csr, N, bshift);

    // ---- layer 1 ----
    transform_k<<<1024, 256, 0, stream>>>(x, W1_rel, W1_root, b1, bufA, bufB, N, 0);
    agg_k<<<(N + 3) / 4, 256, 0, stream>>>(row_ptr, csr, (const unsigned short*)bufA, bufB, N);

    // ---- layer 2 (relu folded on read; in-place on bufB) ----
    transform_k<<<1024, 256, 0, stream>>>(bufB, W2_rel, W2_root, b2, bufA, bufB, N, 1);
    agg_k<<<(N + 3) / 4, 256, 0, stream>>>(row_ptr, csr, (const unsigned short*)bufA, bufB, N);

    // ---- head ----
    final_fc_k<<<(N + 255) / 256, 256, 0, stream>>>(bufB, W_fc, b_fc, out, N);
}

// Round 4
// 214.668 us; speedup vs baseline: 3.6980x; 1.2453x over previous
//
#include <hip/hip_runtime.h>
#include <hip/hip_bf16.h>

using bf16x8 = __attribute__((ext_vector_type(8))) __bf16;
using f32x4  = __attribute__((ext_vector_type(4))) float;

// ============ CSR build (deterministic two-level binning, bshift=8) ============
// Self-detecting edge dtype: wave 0 ballots the odd 32-bit words (all zero => int64).

__global__ __launch_bounds__(256) void bin_hist_k(
    const int* __restrict__ e32, const long long* __restrict__ e64,
    int* __restrict__ blockhist /*[B1][NB]*/, int E, int NB, int bshift, int chunk)
{
    __shared__ int hist[512];
    __shared__ int sflag;
    const int tid = threadIdx.x;
    if (tid < 64) {
        unsigned long long b = __ballot(e32[2 * tid + 1] != 0);
        if (tid == 0) sflag = (b == 0ULL);
    }
    for (int i = tid; i < NB; i += 256) hist[i] = 0;
    __syncthreads();
    const bool i64f = (sflag != 0);
    const int base = blockIdx.x * chunk;
    const int end  = min(base + chunk, E);
    for (int i = base + tid; i < end; i += 256) {
        int d = i64f ? (int)e64[(size_t)E + i] : e32[(size_t)E + i];
        atomicAdd(&hist[d >> bshift], 1);
    }
    __syncthreads();
    int* row = blockhist + (size_t)blockIdx.x * NB;
    for (int b = tid; b < NB; b += 256) row[b] = hist[b];
}

__global__ __launch_bounds__(256) void scanA_k(
    const int* __restrict__ blockhist, int* __restrict__ bh_ex /*[NB][B1]*/,
    int* __restrict__ btot, int NB, int B1)
{
    __shared__ int v[256];
    const int t = threadIdx.x, b = blockIdx.x;
    int x = (t < B1) ? blockhist[(size_t)t * NB + b] : 0;
    v[t] = x; __syncthreads();
    for (int off = 1; off < 256; off <<= 1) {
        int y = (t >= off) ? v[t - off] : 0;
        __syncthreads();
        v[t] += y;
        __syncthreads();
    }
    if (t < B1) bh_ex[(size_t)b * B1 + t] = v[t] - x;
    if (t == 255) btot[b] = v[255];
}

__global__ __launch_bounds__(256) void scanB_k(
    const int* __restrict__ btot, int* __restrict__ bucket_base,
    int* __restrict__ row_ptr, int NB, int N)
{
    __shared__ int ts[256];
    const int t = threadIdx.x;
    int v[4], s = 0;
#pragma unroll
    for (int j = 0; j < 4; ++j) { int i = t * 4 + j; v[j] = (i < NB) ? btot[i] : 0; s += v[j]; }
    ts[t] = s; __syncthreads();
    for (int off = 1; off < 256; off <<= 1) {
        int x = (t >= off) ? ts[t - off] : 0;
        __syncthreads();
        ts[t] += x;
        __syncthreads();
    }
    int base = ts[t] - s;
#pragma unroll
    for (int j = 0; j < 4; ++j) {
        int i = t * 4 + j;
        if (i < NB) { bucket_base[i] = base; base += v[j]; }
    }
    if (t == 255) { bucket_base[NB] = ts[255]; row_ptr[N] = ts[255]; }
}

__global__ __launch_bounds__(256) void bin_scatter_k(
    const int* __restrict__ e32, const long long* __restrict__ e64,
    const int* __restrict__ bh_ex, const int* __restrict__ bucket_base,
    int* __restrict__ pairs, int E, int NB, int B1, int bshift, int chunk)
{
    __shared__ int ofs[512];
    __shared__ int cnt[512];
    __shared__ int sflag;
    const int tid = threadIdx.x;
    if (tid < 64) {
        unsigned long long b = __ballot(e32[2 * tid + 1] != 0);
        if (tid == 0) sflag = (b == 0ULL);
    }
    for (int b = tid; b < NB; b += 256) {
        ofs[b] = bucket_base[b] + bh_ex[(size_t)b * B1 + blockIdx.x];
        cnt[b] = 0;
    }
    __syncthreads();
    const bool i64f = (sflag != 0);
    const int base = blockIdx.x * chunk;
    const int end  = min(base + chunk, E);
    const int mask = (1 << bshift) - 1;
    for (int i = base + tid; i < end; i += 256) {
        int s, d;
        if (i64f) { s = (int)e64[i]; d = (int)e64[(size_t)E + i]; }
        else      { s = e32[i];      d = e32[(size_t)E + i]; }
        int b = d >> bshift;
        int r = atomicAdd(&cnt[b], 1);
        pairs[ofs[b] + r] = (s << bshift) | (d & mask);
    }
}

__global__ __launch_bounds__(256) void buildcsr_k(
    const int* __restrict__ pairs, const int* __restrict__ bucket_base,
    int* __restrict__ row_ptr, int* __restrict__ csr, int N, int bshift)
{
    __shared__ int nh[256], sc[256], cur[256];
    const int t = threadIdx.x, b = blockIdx.x;
    const int n0 = b << bshift;
    const int nn = min(1 << bshift, N - n0);
    const int start = bucket_base[b], end = bucket_base[b + 1];
    const int mask = (1 << bshift) - 1;
    nh[t] = 0;
    __syncthreads();
    for (int i = start + t; i < end; i += 256)
        atomicAdd(&nh[pairs[i] & mask], 1);
    __syncthreads();
    sc[t] = nh[t];
    __syncthreads();
    for (int off = 1; off < 256; off <<= 1) {
        int y = (t >= off) ? sc[t - off] : 0;
        __syncthreads();
        sc[t] += y;
        __syncthreads();
    }
    if (t < nn) {
        int rp = start + sc[t] - nh[t];
        row_ptr[n0 + t] = rp;
        cur[t] = rp;
    }
    __syncthreads();
    for (int i = start + t; i < end; i += 256) {
        int p = pairs[i];
        int pos = atomicAdd(&cur[p & mask], 1);
        csr[pos] = p >> bshift;
    }
}

// ============ fused dual-GEMM via MFMA: [rows x 64] @ [64 x 128] bf16 ============
// cols 0..63 -> rel ; cols 64..127 -> root (+bias). MODE 0: f32 in, no relu.
// MODE 1: bf16 in, relu. A and B frags use the SAME (lanegroup,elem)->k mapping,
// so correctness is independent of the HW's internal k permutation.
template<int MODE>
__global__ __launch_bounds__(256) void transform_mfma_k(
    const void* __restrict__ inv, const float* __restrict__ Wrel,
    const float* __restrict__ Wroot, const float* __restrict__ bias,
    __hip_bfloat16* __restrict__ outRel, __hip_bfloat16* __restrict__ outRoot,
    int nrows)
{
    const int tid = threadIdx.x;
    const int w = tid >> 6, l = tid & 63;
    const int rowHalf = w & 1, colHalf = w >> 1;
    const int lr = l & 15, lg = l >> 4;

    // B fragments (block-invariant): B[k][j] = W'[j][k]
    bf16x8 Bf[4][2];
    float bval[4];
#pragma unroll
    for (int jt = 0; jt < 4; ++jt) {
        int col = colHalf * 64 + jt * 16 + lr;
        const float* wrow = (col < 64) ? (Wrel + (size_t)col * 64)
                                       : (Wroot + (size_t)(col - 64) * 64);
#pragma unroll
        for (int kb = 0; kb < 2; ++kb) {
            const float4* p = (const float4*)(wrow + kb * 32 + lg * 8);
            float4 a = p[0], b = p[1];
            bf16x8 v;
            v[0] = (__bf16)a.x; v[1] = (__bf16)a.y; v[2] = (__bf16)a.z; v[3] = (__bf16)a.w;
            v[4] = (__bf16)b.x; v[5] = (__bf16)b.y; v[6] = (__bf16)b.z; v[7] = (__bf16)b.w;
            Bf[jt][kb] = v;
        }
        bval[jt] = (col >= 64) ? bias[col - 64] : 0.f;
    }

    for (int tile = blockIdx.x * 32; tile < nrows; tile += gridDim.x * 32) {
        int arow = tile + rowHalf * 16 + lr;
        int crow = min(arow, nrows - 1);
        bf16x8 Af[2];
#pragma unroll
        for (int kb = 0; kb < 2; ++kb) {
            float xv[8];
            if (MODE == 0) {
                const float4* p = (const float4*)((const float*)inv + (size_t)crow * 64 + kb * 32 + lg * 8);
                float4 a = p[0], b = p[1];
                xv[0]=a.x; xv[1]=a.y; xv[2]=a.z; xv[3]=a.w;
                xv[4]=b.x; xv[5]=b.y; xv[6]=b.z; xv[7]=b.w;
            } else {
                const ushort4* p = (const ushort4*)((const unsigned short*)inv + (size_t)crow * 64 + kb * 32 + lg * 8);
                ushort4 a = p[0], b = p[1];
                xv[0]=__uint_as_float((unsigned)a.x<<16); xv[1]=__uint_as_float((unsigned)a.y<<16);
                xv[2]=__uint_as_float((unsigned)a.z<<16); xv[3]=__uint_as_float((unsigned)a.w<<16);
                xv[4]=__uint_as_float((unsigned)b.x<<16); xv[5]=__uint_as_float((unsigned)b.y<<16);
                xv[6]=__uint_as_float((unsigned)b.z<<16); xv[7]=__uint_as_float((unsigned)b.w<<16);
#pragma unroll
                for (int e = 0; e < 8; ++e) xv[e] = fmaxf(xv[e], 0.f);
            }
            bf16x8 v;
#pragma unroll
            for (int e = 0; e < 8; ++e) v[e] = (__bf16)xv[e];
            Af[kb] = v;
        }

        f32x4 acc[4];
#pragma unroll
        for (int jt = 0; jt < 4; ++jt) {
            acc[jt][0] = 0.f; acc[jt][1] = 0.f; acc[jt][2] = 0.f; acc[jt][3] = 0.f;
#pragma unroll
            for (int kb = 0; kb < 2; ++kb)
                acc[jt] = __builtin_amdgcn_mfma_f32_16x16x32_bf16(Af[kb], Bf[jt][kb], acc[jt], 0, 0, 0);
        }

        // D layout: col = lane&15, row = (lane>>4)*4 + reg  [HW-verified]
#pragma unroll
        for (int jt = 0; jt < 4; ++jt) {
            int col = colHalf * 64 + jt * 16 + lr;
#pragma unroll
            for (int r = 0; r < 4; ++r) {
                int row = tile + rowHalf * 16 + lg * 4 + r;
                if (row < nrows) {
                    float v = acc[jt][r];
                    if (col < 64)
                        outRel[(size_t)row * 64 + col] = __float2bfloat16(v);
                    else
                        outRoot[(size_t)row * 64 + (col - 64)] = __float2bfloat16(v + bval[jt]);
                }
            }
        }
    }
}

// ============ CSR gather-aggregate (bf16 in/out, f32 accumulate) ============
__global__ __launch_bounds__(256) void agg_k(
    const int* __restrict__ row_ptr, const int* __restrict__ csr,
    const unsigned short* __restrict__ rel, unsigned short* __restrict__ accb, int N)
{
    int node = blockIdx.x * 4 + (threadIdx.x >> 6);
    if (node >= N) return;
    int lane = threadIdx.x & 63;
    int start = row_ptr[node], end = row_ptr[node + 1];
    float acc = __uint_as_float((unsigned)accb[(size_t)node * 64 + lane] << 16);
    int e = start;
    for (; e + 4 <= end; e += 4) {
        int s0 = csr[e], s1 = csr[e + 1], s2 = csr[e + 2], s3 = csr[e + 3];
        unsigned short a0 = rel[(size_t)s0 * 64 + lane];
        unsigned short a1 = rel[(size_t)s1 * 64 + lane];
        unsigned short a2 = rel[(size_t)s2 * 64 + lane];
        unsigned short a3 = rel[(size_t)s3 * 64 + lane];
        acc += __uint_as_float((unsigned)a0 << 16) + __uint_as_float((unsigned)a1 << 16)
             + __uint_as_float((unsigned)a2 << 16) + __uint_as_float((unsigned)a3 << 16);
    }
    for (; e < end; ++e)
        acc += __uint_as_float((unsigned)rel[(size_t)csr[e] * 64 + lane] << 16);
    __hip_bfloat16 hb = __float2bfloat16(acc);
    accb[(size_t)node * 64 + lane] = *(unsigned short*)&hb;
}

// ============ FC head: out[n] = relu(h[n]) . Wfc + bfc (h in bf16) ============
__global__ __launch_bounds__(256) void final_fc_k(
    const unsigned short* __restrict__ h, const float* __restrict__ Wfc,
    const float* __restrict__ bfc, float* __restrict__ out, int nrows)
{
    int n = blockIdx.x * 256 + threadIdx.x;
    if (n >= nrows) return;
    float acc = bfc[0];
    const ushort4* hp = (const ushort4*)(h + (size_t)n * 64);
    const float4* wp = (const float4*)Wfc;
#pragma unroll
    for (int q = 0; q < 16; ++q) {
        ushort4 u = hp[q];
        float4 wv = wp[q];
        acc += fmaxf(__uint_as_float((unsigned)u.x << 16), 0.f) * wv.x
             + fmaxf(__uint_as_float((unsigned)u.y << 16), 0.f) * wv.y
             + fmaxf(__uint_as_float((unsigned)u.z << 16), 0.f) * wv.z
             + fmaxf(__uint_as_float((unsigned)u.w << 16), 0.f) * wv.w;
    }
    out[n] = acc;
}

extern "C" void kernel_launch(void* const* d_in, const int* in_sizes, int n_in,
                              void* d_out, int out_size, void* d_ws, size_t ws_size,
                              hipStream_t stream) {
    const float* x       = (const float*)d_in[0];
    const int* e32       = (const int*)d_in[1];
    const long long* e64 = (const long long*)d_in[1];
    const float* W1_rel  = (const float*)d_in[2];
    const float* W1_root = (const float*)d_in[3];
    const float* b1      = (const float*)d_in[4];
    const float* W2_rel  = (const float*)d_in[5];
    const float* W2_root = (const float*)d_in[6];
    const float* b2      = (const float*)d_in[7];
    const float* W_fc    = (const float*)d_in[8];
    const float* b_fc    = (const float*)d_in[9];
    float* out           = (float*)d_out;

    const int N = in_sizes[0] / 64;    // 100000
    const int E = in_sizes[1] / 2;     // 1600000

    const int bshift = 8;                                  // 256 nodes/bucket
    const int NB = (N + (1 << bshift) - 1) >> bshift;      // 391 (<=512)
    int chunk = 8192;
    while ((E + chunk - 1) / chunk > 256) chunk <<= 1;
    const int B1 = (E + chunk - 1) / chunk;                // 196

    // workspace (~52 MB)
    char* p = (char*)d_ws;
    unsigned short* bufA   = (unsigned short*)p; p += (size_t)N * 64 * 2;  // root1 / h1
    unsigned short* bufB   = (unsigned short*)p; p += (size_t)N * 64 * 2;  // root2 / h2
    unsigned short* bufRel = (unsigned short*)p; p += (size_t)N * 64 * 2;  // rel (both layers)
    int* csr         = (int*)p;  p += (size_t)E * 4;
    int* pairs       = (int*)p;  p += (size_t)E * 4;
    int* row_ptr     = (int*)p;  p += (size_t)(N + 1) * 4;
    int* blockhist   = (int*)p;  p += (size_t)B1 * NB * 4;
    int* bh_ex       = (int*)p;  p += (size_t)NB * B1 * 4;
    int* btot        = (int*)p;  p += (size_t)NB * 4;
    int* bucket_base = (int*)p;

    // ---- CSR build ----
    bin_hist_k<<<B1, 256, 0, stream>>>(e32, e64, blockhist, E, NB, bshift, chunk);
    scanA_k<<<NB, 256, 0, stream>>>(blockhist, bh_ex, btot, NB, B1);
    scanB_k<<<1, 256, 0, stream>>>(btot, bucket_base, row_ptr, NB, N);
    bin_scatter_k<<<B1, 256, 0, stream>>>(e32, e64, bh_ex, bucket_base, pairs,
                                          E, NB, B1, bshift, chunk);
    buildcsr_k<<<NB, 256, 0, stream>>>(pairs, bucket_base, row_ptr, csr, N, bshift);

    // ---- layer 1 ----
    transform_mfma_k<0><<<1024, 256, 0, stream>>>(x, W1_rel, W1_root, b1,
        (__hip_bfloat16*)bufRel, (__hip_bfloat16*)bufA, N);
    agg_k<<<(N + 3) / 4, 256, 0, stream>>>(row_ptr, csr, bufRel, bufA, N);

    // ---- layer 2 ----
    transform_mfma_k<1><<<1024, 256, 0, stream>>>(bufA, W2_rel, W2_root, b2,
        (__hip_bfloat16*)bufRel, (__hip_bfloat16*)bufB, N);
    agg_k<<<(N + 3) / 4, 256, 0, stream>>>(row_ptr, csr, bufRel, bufB, N);

    // ---- head ----
    final_fc_k<<<(N + 255) / 256, 256, 0, stream>>>(bufB, W_fc, b_fc, out, N);
}